// Round 2
// baseline (80751.019 us; speedup 1.0000x reference)
//
#include <hip/hip_runtime.h>

// ---------------- problem constants ----------------
#define NTHR 256

constexpr int Bsz = 256, Tt = 400, Ff = 76, Hh = 768, Ll = 8, Kw = 10, Ss = 128, Cc = 96, Gg = 3088;
constexpr int KD1 = Ff + Hh;            // 844 (recurrent GEMM inner dim; bias rows folded)
constexpr int NKS = 15;                 // conv K-splits of 512 over kc = k*768+c (7680 total)
constexpr int CONV_JOBS = 4 * 12 * NKS; // bt(4 x 64b) * ot(12 x 64o) * 15 splits = 720
constexpr int TH1_JOBS = 8;             // 4 x 2 tiles of 64x64
constexpr int G1_JOBS = 4 * 49;         // 64x64 tiles over 256 x 3088 = 196

// ---------------- workspace layout (floats) ----------------
constexpr size_t O_Z   = 0;                                  // B*G   z (bias folded)
constexpr size_t O_ZB  = O_Z   + (size_t)Bsz * Gg;           // G     zbias
constexpr size_t O_HR  = O_ZB  + (size_t)Gg;                 // Kw*B*H  h ring
constexpr size_t O_CB  = O_HR  + (size_t)Kw * Bsz * Hh;      // B*H    cell state
constexpr size_t O_DR  = O_CB  + (size_t)Bsz * Hh;           // Kw*B   dis ring
constexpr size_t O_LD  = O_DR  + (size_t)Kw * Bsz;           // 2*B*Kw local_dis
constexpr size_t O_HM  = O_LD  + (size_t)2 * Bsz * Kw;       // B*H    hmean
constexpr size_t O_T1  = O_HM  + (size_t)Bsz * Hh;           // B*S    theme1
constexpr size_t O_CP  = O_T1  + (size_t)Bsz * Ss;           // NKS*B*H conv partials (11.8 MB)
constexpr size_t O_CWT = O_CP  + (size_t)NKS * Bsz * Hh;     // H*H*Kw transposed conv_w (23.6 MB)
constexpr size_t WS_FL = O_CWT + (size_t)Hh * Hh * Kw;       // ~48.2 MB total

struct SP {
  const float *x, *kw, *kb, *rw, *rb, *sw, *sb, *rsw, *rsb, *cw, *cb, *ow, *ob;
  float *z, *zbias, *hring, *cbuf, *dring, *ldis, *hmean, *th1, *cpart, *cwt, *out;
};

__device__ __forceinline__ float sigf(float v) { return 1.f / (1.f + __expf(-v)); }
__device__ __forceinline__ float tanhfast(float v) {
  float e = __expf(2.f * fminf(v, 15.f));   // clamp avoids inf/inf; tanh(15)~1 in fp32
  return (e - 1.f) / (e + 1.f);
}

// ---------------- setup kernels ----------------
__global__ void k_setup(SP p) {
  size_t i0 = (size_t)blockIdx.x * NTHR + threadIdx.x;
  size_t stride = (size_t)gridDim.x * NTHR;
  // zero [hring | cbuf | dring] (contiguous in layout)
  size_t n = (size_t)Kw * Bsz * Hh + (size_t)Bsz * Hh + (size_t)Kw * Bsz;
  for (size_t i = i0; i < n; i += stride) p.hring[i] = 0.f;
  // zbias = kernel_w ones-row + kernel_b + rec_w ones-row + rec_b
  for (size_t g = i0; g < (size_t)Gg; g += stride)
    p.zbias[g] = p.kw[(size_t)Ff * Gg + g] + p.kb[g] + p.rw[(size_t)Hh * Gg + g] + p.rb[g];
}

// cwt[(k*H + c)*H + o] = conv_w[o][c][k]
__global__ void k_transpose(SP p) {
  size_t total = (size_t)Hh * Hh * Kw;
  size_t stride = (size_t)gridDim.x * NTHR;
  for (size_t i = (size_t)blockIdx.x * NTHR + threadIdx.x; i < total; i += stride) {
    int o = (int)(i % Hh);
    size_t r = i / Hh;
    int c = (int)(r % Hh);
    int k = (int)(r / Hh);
    p.cwt[i] = p.cw[((size_t)o * Hh + c) * Kw + k];
  }
}

__global__ void k_fill(float* o, int n, float v) {
  int i = blockIdx.x * NTHR + threadIdx.x;
  if (i < n) o[i] = v;
}

// ---------------- GEMM jobs (fp32, LDS-staged, float4 micro reads) ----------------
// All use 64x64 tiles, 4x4 micro, K-chunks of 32, LDS stride 68 (272B = 17*16B aligned).

// z(t) = [x_t | h_{t-1}] @ [kernel_w ; rec_w] + zbias
__device__ void gemm1_job(const SP& p, int j, int t, float* As, float* Ws) {
  const int tid = threadIdx.x;
  const int mt = j / 49, nt = j % 49;
  const int b0 = mt * 64, g0 = nt * 64;
  const int slotp = (t + Kw - 1) % Kw;   // h_{t-1}
  const float* hsrc = p.hring + (size_t)slotp * (Bsz * Hh);
  float acc[4][4] = {};
  const int tn = tid & 15, tm = tid >> 4;
  for (int c = 0; c < KD1; c += 32) {
    { // A: 64 rows(b) x 32 cols(kd); As[col*68 + m]
      const int col = tid & 31, rb = tid >> 5;
      #pragma unroll
      for (int i = 0; i < 8; ++i) {
        int m = rb + i * 8, b = b0 + m, kd = c + col;
        float v = 0.f;
        if (kd < KD1)
          v = (kd < Ff) ? p.x[(size_t)b * (Tt * Ff) + (size_t)t * Ff + kd]
                        : hsrc[(size_t)b * Hh + (kd - Ff)];
        As[col * 68 + m] = v;
      }
    }
    { // W: 32 rows(kd) x 64 cols(g); Ws[kr*68 + col]
      const int col = tid & 63, rb = tid >> 6;
      #pragma unroll
      for (int i = 0; i < 8; ++i) {
        int kr = rb + i * 4, kd = c + kr, g = g0 + col;
        float v = 0.f;
        if (kd < KD1 && g < Gg)
          v = (kd < Ff) ? p.kw[(size_t)kd * Gg + g] : p.rw[(size_t)(kd - Ff) * Gg + g];
        Ws[kr * 68 + col] = v;
      }
    }
    __syncthreads();
    #pragma unroll
    for (int kk = 0; kk < 32; ++kk) {
      float4 a  = *reinterpret_cast<const float4*>(As + kk * 68 + tm * 4);
      float4 bv = *reinterpret_cast<const float4*>(Ws + kk * 68 + tn * 4);
      float av[4] = {a.x, a.y, a.z, a.w};
      float bb[4] = {bv.x, bv.y, bv.z, bv.w};
      #pragma unroll
      for (int i = 0; i < 4; ++i)
        #pragma unroll
        for (int jj = 0; jj < 4; ++jj) acc[i][jj] = fmaf(av[i], bb[jj], acc[i][jj]);
    }
    __syncthreads();
  }
  #pragma unroll
  for (int i = 0; i < 4; ++i) {
    int b = b0 + tm * 4 + i;
    #pragma unroll
    for (int jj = 0; jj < 4; ++jj) {
      int g = g0 + tn * 4 + jj;
      if (g < Gg) p.z[(size_t)b * Gg + g] = acc[i][jj] + p.zbias[g];
    }
  }
}

// conv partial over a 512-wide kc split: cpart[ks][b][o] = sum_{kc in split} A[b,kc]*cwt[kc][o]
// A[b, k*768+c] = hring[slot(k)][b][c] * local_dis[b][k].  Each 32-chunk stays within one k.
__device__ void conv_job(const SP& p, int j, int t, float* As, float* Ws) {
  const int tid = threadIdx.x;
  const int bt = j / (12 * NKS);
  const int r  = j % (12 * NKS);
  const int ot = r / NKS;
  const int ks = r % NKS;
  const int b0 = bt * 64, o0 = ot * 64, kc0 = ks * 512;
  const float* lsrc = p.ldis + (size_t)(t & 1) * (Bsz * Kw);
  float acc[4][4] = {};
  const int tn = tid & 15, tm = tid >> 4;
  for (int cc = 0; cc < 512; cc += 32) {
    const int kc = kc0 + cc;
    const int k = kc / Hh;               // constant within the 32-chunk (32 | 768)
    const int cb = kc % Hh;
    const int slot = (t + 1 + k) % Kw;   // ring slot of h_{t-9+k} (zeros pre-start)
    const float* hsrc = p.hring + (size_t)slot * (Bsz * Hh);
    { // A: 64 rows(b) x 32 cols(kc), scaled by local_dis[b][k]
      const int col = tid & 31, rb = tid >> 5;
      #pragma unroll
      for (int i = 0; i < 8; ++i) {
        int m = rb + i * 8, b = b0 + m;
        As[col * 68 + m] = hsrc[(size_t)b * Hh + (cb + col)] * lsrc[b * Kw + k];
      }
    }
    { // W: 32 rows(kc) x 64 cols(o)
      const int col = tid & 63, rb = tid >> 6;
      #pragma unroll
      for (int i = 0; i < 8; ++i) {
        int kr = rb + i * 4;
        Ws[kr * 68 + col] = p.cwt[(size_t)(kc + kr) * Hh + (o0 + col)];
      }
    }
    __syncthreads();
    #pragma unroll
    for (int kk = 0; kk < 32; ++kk) {
      float4 a  = *reinterpret_cast<const float4*>(As + kk * 68 + tm * 4);
      float4 bv = *reinterpret_cast<const float4*>(Ws + kk * 68 + tn * 4);
      float av[4] = {a.x, a.y, a.z, a.w};
      float bb[4] = {bv.x, bv.y, bv.z, bv.w};
      #pragma unroll
      for (int i = 0; i < 4; ++i)
        #pragma unroll
        for (int jj = 0; jj < 4; ++jj) acc[i][jj] = fmaf(av[i], bb[jj], acc[i][jj]);
    }
    __syncthreads();
  }
  float* dst = p.cpart + (size_t)ks * (Bsz * Hh);
  #pragma unroll
  for (int i = 0; i < 4; ++i) {
    int b = b0 + tm * 4 + i;
    #pragma unroll
    for (int jj = 0; jj < 4; ++jj)
      dst[(size_t)b * Hh + (o0 + tn * 4 + jj)] = acc[i][jj];
  }
}

// theme1 = relu(hmean @ scale_w + scale_b)
__device__ void theme1_job(const SP& p, int j, float* As, float* Ws) {
  const int tid = threadIdx.x;
  const int mt = j & 3, nt = j >> 2;
  const int b0 = mt * 64, s0 = nt * 64;
  float acc[4][4] = {};
  const int tn = tid & 15, tm = tid >> 4;
  for (int c = 0; c < Hh; c += 32) {
    {
      const int col = tid & 31, rb = tid >> 5;
      #pragma unroll
      for (int i = 0; i < 8; ++i) {
        int m = rb + i * 8, b = b0 + m;
        As[col * 68 + m] = p.hmean[(size_t)b * Hh + (c + col)];
      }
    }
    {
      const int col = tid & 63, rb = tid >> 6;
      #pragma unroll
      for (int i = 0; i < 8; ++i) {
        int kr = rb + i * 4;
        Ws[kr * 68 + col] = p.sw[(size_t)(c + kr) * Ss + (s0 + col)];
      }
    }
    __syncthreads();
    #pragma unroll
    for (int kk = 0; kk < 32; ++kk) {
      float4 a  = *reinterpret_cast<const float4*>(As + kk * 68 + tm * 4);
      float4 bv = *reinterpret_cast<const float4*>(Ws + kk * 68 + tn * 4);
      float av[4] = {a.x, a.y, a.z, a.w};
      float bb[4] = {bv.x, bv.y, bv.z, bv.w};
      #pragma unroll
      for (int i = 0; i < 4; ++i)
        #pragma unroll
        for (int jj = 0; jj < 4; ++jj) acc[i][jj] = fmaf(av[i], bb[jj], acc[i][jj]);
    }
    __syncthreads();
  }
  #pragma unroll
  for (int i = 0; i < 4; ++i) {
    int b = b0 + tm * 4 + i;
    #pragma unroll
    for (int jj = 0; jj < 4; ++jj) {
      int s = s0 + tn * 4 + jj;
      p.th1[(size_t)b * Ss + s] = fmaxf(acc[i][jj] + p.sb[s], 0.f);
    }
  }
}

// ---------------- per-b phases ----------------
__device__ void gates_phase(const SP& p, int b, int t, float* misc) {
  const int tid = threadIdx.x;
  float* sh  = misc;            // 768  h_new
  float* sfm = misc + Hh;       // 8
  float* sim = misc + Hh + 8;   // 8
  float* sld = misc + Hh + 16;  // 10
  const int slot_t = t % Kw;
  if (tid == 0) {
    const float* zrow = p.z + (size_t)b * Gg;
    float e[Ll], mx, ssum, inv, run;
    // fm = cumsum(softmax(z[:8]))
    mx = -1e30f;
    for (int l = 0; l < Ll; ++l) mx = fmaxf(mx, zrow[l]);
    ssum = 0.f;
    for (int l = 0; l < Ll; ++l) { e[l] = __expf(zrow[l] - mx); ssum += e[l]; }
    inv = 1.f / ssum; run = 0.f;
    float fmsum = 0.f;
    for (int l = 0; l < Ll; ++l) { run += e[l] * inv; sfm[l] = run; fmsum += run; }
    // im[l] = sum_{m>=l} softmax(z[8:16])[m]
    mx = -1e30f;
    for (int l = 0; l < Ll; ++l) mx = fmaxf(mx, zrow[Ll + l]);
    ssum = 0.f;
    for (int l = 0; l < Ll; ++l) { e[l] = __expf(zrow[Ll + l] - mx); ssum += e[l]; }
    inv = 1.f / ssum; run = 0.f;
    for (int l = Ll - 1; l >= 0; --l) { run += e[l] * inv; sim[l] = run; }
    float cdis = 1.f - fmsum * (1.f / Ll);
    p.dring[slot_t * Bsz + b] = cdis;
    // local_dis = softmax(cumsum(dis window))
    float dw[Kw], cm[Kw];
    for (int k = 0; k < Kw; ++k) {
      int slot = (t + 1 + k) % Kw;                 // slot of dis_{t-9+k}; pre-start = 0
      dw[k] = (k == Kw - 1) ? cdis : p.dring[slot * Bsz + b];
    }
    float cs = 0.f, mx2 = -1e30f;
    for (int k = 0; k < Kw; ++k) { cs += dw[k]; cm[k] = cs; mx2 = fmaxf(mx2, cs); }
    float s2 = 0.f;
    for (int k = 0; k < Kw; ++k) { cm[k] = __expf(cm[k] - mx2); s2 += cm[k]; }
    float i2 = 1.f / s2;
    for (int k = 0; k < Kw; ++k) {
      float v = cm[k] * i2;
      sld[k] = v;
      p.ldis[(size_t)(t & 1) * (Bsz * Kw) + b * Kw + k] = v;
    }
  }
  __syncthreads();
  const float* zg = p.z + (size_t)b * Gg + 2 * Ll;
  for (int idx = tid; idx < Hh; idx += NTHR) {
    int l = idx / Cc;
    float f  = sigf(zg[idx]);
    float ii = sigf(zg[Hh + idx]);
    float oo = sigf(zg[2 * Hh + idx]);
    float ci = tanhfast(zg[3 * Hh + idx]);
    float cl = p.cbuf[(size_t)b * Hh + idx];
    float fm = sfm[l], im = sim[l], ov = fm * im;
    float cn = ov * (f * cl + ii * ci) + (fm - ov) * cl + (im - ov) * ci;
    float hn = oo * tanhfast(cn);
    p.cbuf[(size_t)b * Hh + idx] = cn;
    p.hring[(size_t)slot_t * (Bsz * Hh) + (size_t)b * Hh + idx] = hn;
    sh[idx] = hn;
  }
  __syncthreads();
  // hmean = mean_k( h_window[k] * local_dis[k] )
  for (int idx = tid; idx < Hh; idx += NTHR) {
    float a = sh[idx] * sld[Kw - 1];
    #pragma unroll
    for (int k = 0; k < Kw - 1; ++k) {
      int slot = (t + 1 + k) % Kw;
      a += p.hring[(size_t)slot * (Bsz * Hh) + (size_t)b * Hh + idx] * sld[k];
    }
    p.hmean[(size_t)b * Hh + idx] = a * (1.f / Kw);
  }
}

// theme = sigmoid(theme1 @ rescale_w + rescale_b); out = sigmoid(dot(theme*conv + h, out_w) + ob)
__device__ void combine_phase(const SP& p, int b0, int t, float* misc) {
  const int tid = threadIdx.x;
  float* st1  = misc;        // 4*128 theme1 rows
  float* sred = misc + 512;  // 16
  for (int i = tid; i < 4 * Ss; i += NTHR) st1[i] = p.th1[(size_t)b0 * Ss + i];
  __syncthreads();
  const int slot_t = t % Kw;
  float dot0 = 0, dot1 = 0, dot2 = 0, dot3 = 0;
  for (int o = tid; o < Hh; o += NTHR) {
    float rb = p.rsb[o];
    float t0 = rb, t1 = rb, t2 = rb, t3 = rb;
    for (int s = 0; s < Ss; ++s) {
      float w = p.rsw[(size_t)s * Hh + o];
      t0 = fmaf(st1[s], w, t0);
      t1 = fmaf(st1[Ss + s], w, t1);
      t2 = fmaf(st1[2 * Ss + s], w, t2);
      t3 = fmaf(st1[3 * Ss + s], w, t3);
    }
    float cbv = p.cb[o];
    float c0 = cbv, c1 = cbv, c2 = cbv, c3 = cbv;
    for (int ks = 0; ks < NKS; ++ks) {
      const float* cp = p.cpart + (size_t)ks * (Bsz * Hh) + (size_t)b0 * Hh + o;
      c0 += cp[0]; c1 += cp[Hh]; c2 += cp[2 * (size_t)Hh]; c3 += cp[3 * (size_t)Hh];
    }
    float oww = p.ow[o];
    const float* hr = p.hring + (size_t)slot_t * (Bsz * Hh) + (size_t)b0 * Hh + o;
    dot0 += (sigf(t0) * c0 + hr[0]) * oww;
    dot1 += (sigf(t1) * c1 + hr[Hh]) * oww;
    dot2 += (sigf(t2) * c2 + hr[2 * (size_t)Hh]) * oww;
    dot3 += (sigf(t3) * c3 + hr[3 * (size_t)Hh]) * oww;
  }
  float d[4] = {dot0, dot1, dot2, dot3};
  #pragma unroll
  for (int q = 0; q < 4; ++q) {
    float v = d[q];
    for (int off = 32; off > 0; off >>= 1) v += __shfl_down(v, off);
    if ((tid & 63) == 0) sred[(tid >> 6) * 4 + q] = v;
  }
  __syncthreads();
  if (tid < 4) {
    float v = sred[tid] + sred[4 + tid] + sred[8 + tid] + sred[12 + tid];
    p.out[(size_t)(b0 + tid) * Tt + t] = sigf(v + p.ob[0]);
  }
}

// ---------------- step kernels (stream-ordered; no cooperative launch) ----------------
__global__ void __launch_bounds__(NTHR, 2) k_p1(SP p, int t) {
  __shared__ float misc[Hh + 64];
  const int blk = blockIdx.x;
  if (blk < Bsz) gates_phase(p, blk, t, misc);
  else if (t > 0) combine_phase(p, (blk - 256) * 4, t - 1, misc);
}

__global__ void __launch_bounds__(NTHR, 4) k_p2(SP p, int t) {
  __shared__ float As[32 * 68];
  __shared__ float Ws[32 * 68];
  const int j = blockIdx.x;
  const int njobs = CONV_JOBS + TH1_JOBS + ((t + 1 < Tt) ? G1_JOBS : 0);
  if (j >= njobs) return;
  if (j < CONV_JOBS) conv_job(p, j, t, As, Ws);
  else if (j < CONV_JOBS + TH1_JOBS) theme1_job(p, j - CONV_JOBS, As, Ws);
  else gemm1_job(p, j - CONV_JOBS - TH1_JOBS, t + 1, As, Ws);
}

__global__ void __launch_bounds__(NTHR, 4) k_g1first(SP p) {
  __shared__ float As[32 * 68];
  __shared__ float Ws[32 * 68];
  gemm1_job(p, blockIdx.x, 0, As, Ws);
}

__global__ void __launch_bounds__(NTHR, 2) k_comb_last(SP p) {
  __shared__ float misc[Hh + 64];
  combine_phase(p, blockIdx.x * 4, Tt - 1, misc);
}

// ---------------- host entry ----------------
extern "C" void kernel_launch(void* const* d_in, const int* in_sizes, int n_in,
                              void* d_out, int out_size, void* d_ws, size_t ws_size,
                              hipStream_t stream) {
  (void)in_sizes; (void)n_in;
  SP p;
  p.x   = (const float*)d_in[0];
  p.kw  = (const float*)d_in[1];
  p.kb  = (const float*)d_in[2];
  p.rw  = (const float*)d_in[3];
  p.rb  = (const float*)d_in[4];
  p.sw  = (const float*)d_in[5];
  p.sb  = (const float*)d_in[6];
  p.rsw = (const float*)d_in[7];
  p.rsb = (const float*)d_in[8];
  p.cw  = (const float*)d_in[9];
  p.cb  = (const float*)d_in[10];
  p.ow  = (const float*)d_in[11];
  p.ob  = (const float*)d_in[12];
  float* ws = (float*)d_ws;
  p.z = ws + O_Z;   p.zbias = ws + O_ZB; p.hring = ws + O_HR; p.cbuf = ws + O_CB;
  p.dring = ws + O_DR; p.ldis = ws + O_LD; p.hmean = ws + O_HM; p.th1 = ws + O_T1;
  p.cpart = ws + O_CP; p.cwt = ws + O_CWT;
  p.out = (float*)d_out;

  if (ws_size < WS_FL * sizeof(float)) {
    // sentinel: distinguish "ws too small" (error ~0.49) from "nothing ran" (~0.72)
    k_fill<<<(out_size + NTHR - 1) / NTHR, NTHR, 0, stream>>>((float*)d_out, out_size, 0.5f);
    return;
  }

  k_setup<<<1024, NTHR, 0, stream>>>(p);
  k_transpose<<<1024, NTHR, 0, stream>>>(p);
  k_g1first<<<G1_JOBS, NTHR, 0, stream>>>(p);               // z(0)
  for (int t = 0; t < Tt; ++t) {
    k_p1<<<320, NTHR, 0, stream>>>(p, t);                   // gates(t) || combine(t-1)
    k_p2<<<CONV_JOBS + TH1_JOBS + G1_JOBS, NTHR, 0, stream>>>(p, t); // conv(t)+theme1(t)+z(t+1)
  }
  k_comb_last<<<64, NTHR, 0, stream>>>(p);                  // combine(399)
}

// Round 3
// 26606.024 us; speedup vs baseline: 3.0351x; 3.0351x over previous
//
#include <hip/hip_runtime.h>

#define NTHR 256

constexpr int Bsz = 256, Tt = 400, Ff = 76, Hh = 768, Ll = 8, Kw = 10, Ss = 128, Cc = 96, Gg = 3088;
constexpr int KD1 = Ff + Hh;       // 844
constexpr int A1LD = 864;          // padded K for gemm1 (27*32)
constexpr int GPAD = 3200;         // padded N for gemm1 (25*128)
constexpr int KC = Hh * Kw;        // 7680 conv inner dim
constexpr int SPLITS = 16;         // conv split-K (480 each = 15 k-steps)
constexpr int CONV_JOBS = 2 * 6 * SPLITS;  // 192
constexpr int G1_JOBS = 2 * 25;            // 50
constexpr int TH1_JOBS = 2;
constexpr int P2_GRID = CONV_JOBS + G1_JOBS + TH1_JOBS;  // 244

// ---------------- workspace layout ----------------
// fp32 region (float offsets)
constexpr size_t O_Z   = 0;                                   // B*G
constexpr size_t O_ZB  = O_Z  + (size_t)Bsz * Gg;             // G
constexpr size_t O_HR  = O_ZB + 3088;                         // Kw*B*H
constexpr size_t O_CB  = O_HR + (size_t)Kw * Bsz * Hh;        // B*H
constexpr size_t O_DR  = O_CB + (size_t)Bsz * Hh;             // Kw*B
constexpr size_t O_LD  = O_DR + (size_t)Kw * Bsz;             // 2*B*Kw
constexpr size_t O_TH1 = O_LD + (size_t)2 * Bsz * Kw;         // B*S
constexpr size_t O_CP  = O_TH1 + (size_t)Bsz * Ss;            // SPLITS*B*H
constexpr size_t O_BF  = O_CP + (size_t)SPLITS * Bsz * Hh;    // bf16 region start
// bf16 region (ushort offsets from wsb)
constexpr size_t H_KWB = 0;                                    // GPAD*A1LD
constexpr size_t H_CWT = H_KWB + (size_t)GPAD * A1LD;          // H*KC
constexpr size_t H_SWB = H_CWT + (size_t)Hh * KC;              // S*H
constexpr size_t H_A1  = H_SWB + (size_t)Ss * Hh;              // B*A1LD
constexpr size_t H_AB  = H_A1  + (size_t)Bsz * A1LD;           // B*KC
constexpr size_t H_HM  = H_AB  + (size_t)Bsz * KC;             // B*H
constexpr size_t H_END = H_HM  + (size_t)Bsz * Hh;
constexpr size_t WS_FL = O_BF + (H_END + 1) / 2;               // ~46.9 MB

struct SP {
  const float *x, *kw, *kb, *rw, *rb, *sw, *sb, *rsw, *rsb, *cw, *cb, *ow, *ob;
  float *z, *zbias, *hring, *cbuf, *dring, *ldis, *th1, *cpart, *out;
  ushort *kwb, *cwtb, *swb, *A1, *Ab, *hmb;
};

typedef __attribute__((ext_vector_type(8))) short bf16x8;
typedef __attribute__((ext_vector_type(4))) float f32x4;

__device__ __forceinline__ float sigf(float v) { return 1.f / (1.f + __expf(-v)); }
__device__ __forceinline__ float tanhfast(float v) {
  float e = __expf(2.f * fminf(v, 15.f));
  return (e - 1.f) / (e + 1.f);
}
__device__ __forceinline__ ushort f2bf(float f) {
  union { float f; unsigned u; } x; x.f = f;
  unsigned r = x.u + 0x7fffu + ((x.u >> 16) & 1u);   // RNE
  return (ushort)(r >> 16);
}

// ---------------- setup kernels ----------------
__global__ void k_setup(SP p) {
  size_t i0 = (size_t)blockIdx.x * NTHR + threadIdx.x;
  size_t stride = (size_t)gridDim.x * NTHR;
  size_t n = (size_t)Kw * Bsz * Hh + (size_t)Bsz * Hh + (size_t)Kw * Bsz; // hring|cbuf|dring contiguous
  for (size_t i = i0; i < n; i += stride) p.hring[i] = 0.f;
  for (size_t g = i0; g < (size_t)Gg; g += stride)
    p.zbias[g] = p.kw[(size_t)Ff * Gg + g] + p.kb[g] + p.rw[(size_t)Hh * Gg + g] + p.rb[g];
  // A1 for t=0: x-part = x[b][0], rest zero
  for (size_t i = i0; i < (size_t)Bsz * A1LD; i += stride) {
    int b = (int)(i / A1LD), kd = (int)(i % A1LD);
    p.A1[i] = (kd < Ff) ? f2bf(p.x[(size_t)b * (Tt * Ff) + kd]) : (ushort)0;
  }
}
__global__ void k_wkr(SP p) {  // kwb[g][kd] (padded), bf16
  size_t total = (size_t)GPAD * A1LD;
  size_t stride = (size_t)gridDim.x * NTHR;
  for (size_t i = (size_t)blockIdx.x * NTHR + threadIdx.x; i < total; i += stride) {
    int g = (int)(i / A1LD), kd = (int)(i % A1LD);
    float v = 0.f;
    if (g < Gg && kd < KD1)
      v = (kd < Ff) ? p.kw[(size_t)kd * Gg + g] : p.rw[(size_t)(kd - Ff) * Gg + g];
    p.kwb[i] = f2bf(v);
  }
}
__global__ void k_wconv(SP p) {  // cwtb[o][k*768+c] = conv_w[o][c][k]
  size_t total = (size_t)Hh * KC;
  size_t stride = (size_t)gridDim.x * NTHR;
  for (size_t i = (size_t)blockIdx.x * NTHR + threadIdx.x; i < total; i += stride) {
    int o = (int)(i / KC), r = (int)(i % KC);
    int k = r / Hh, c = r % Hh;
    p.cwtb[i] = f2bf(p.cw[((size_t)o * Hh + c) * Kw + k]);
  }
}
__global__ void k_wsw(SP p) {  // swb[s][h] = sw[h][s]
  size_t total = (size_t)Ss * Hh;
  size_t stride = (size_t)gridDim.x * NTHR;
  for (size_t i = (size_t)blockIdx.x * NTHR + threadIdx.x; i < total; i += stride) {
    int s = (int)(i / Hh), h = (int)(i % Hh);
    p.swb[i] = f2bf(p.sw[(size_t)h * Ss + s]);
  }
}
__global__ void k_fill(float* o, int n, float v) {
  int i = blockIdx.x * NTHR + threadIdx.x;
  if (i < n) o[i] = v;
}

// ---------------- MFMA tile core: block 128x128, 4 waves (2x2), wave 64x64 ----------------
// A: [.][lda] bf16 row-major (rows = M), B: [.][ldb] bf16 row-major PRE-TRANSPOSED (rows = N).
// LDS tile rows of 32 bf16 (64B = 4 x 16B slots), slot swizzle: s' = s ^ ((row>>1)&3)  -> 2-way max.
__device__ __forceinline__ void mfma_tile(const ushort* A, int lda, const ushort* B, int ldb,
                                          int k0, int ksteps, ushort* lsA, ushort* lsB,
                                          f32x4 acc[4][4]) {
  const int tid = threadIdx.x;
  const int lane = tid & 63, wid = tid >> 6;
  const int wm = (wid >> 1) * 64, wn = (wid & 1) * 64;
  const int lr = lane & 15, lg = lane >> 4;
  char* cA = (char*)lsA;
  char* cB = (char*)lsB;
  int offA[4], offB[4];
  #pragma unroll
  for (int f = 0; f < 4; ++f) {
    int m = wm + f * 16 + lr;
    offA[f] = m * 64 + ((lg ^ ((m >> 1) & 3)) << 4);
    int n = wn + f * 16 + lr;
    offB[f] = n * 64 + ((lg ^ ((n >> 1) & 3)) << 4);
  }
  const int sm = (tid * 2) >> 2;        // staging row for this thread (2 slots each)
  const int ss0 = (tid * 2) & 3;
  for (int s = 0; s < ksteps; ++s) {
    const int k = k0 + s * 32;
    #pragma unroll
    for (int i = 0; i < 2; ++i) {
      int idx = i * 256 + tid;
      int m = idx >> 2, sl = idx & 3;
      uint4 va = *reinterpret_cast<const uint4*>(A + (size_t)m * lda + k + sl * 8);
      *reinterpret_cast<uint4*>(cA + m * 64 + ((sl ^ ((m >> 1) & 3)) << 4)) = va;
      uint4 vb = *reinterpret_cast<const uint4*>(B + (size_t)m * ldb + k + sl * 8);
      *reinterpret_cast<uint4*>(cB + m * 64 + ((sl ^ ((m >> 1) & 3)) << 4)) = vb;
    }
    __syncthreads();
    bf16x8 af[4], bfr[4];
    #pragma unroll
    for (int f = 0; f < 4; ++f) {
      af[f]  = *reinterpret_cast<const bf16x8*>(cA + offA[f]);
      bfr[f] = *reinterpret_cast<const bf16x8*>(cB + offB[f]);
    }
    #pragma unroll
    for (int mf = 0; mf < 4; ++mf)
      #pragma unroll
      for (int nf = 0; nf < 4; ++nf)
        acc[mf][nf] = __builtin_amdgcn_mfma_f32_16x16x32_bf16(af[mf], bfr[nf], acc[mf][nf], 0, 0, 0);
    __syncthreads();
  }
  (void)sm; (void)ss0;
}

// ---------------- per-b phases (fp32) ----------------
__device__ void gates_phase(const SP& p, int b, int t, float* misc) {
  const int tid = threadIdx.x;
  float* sh  = misc;            // 768
  float* sfm = misc + Hh;       // 8
  float* sim = misc + Hh + 8;   // 8
  float* sld = misc + Hh + 16;  // 10
  const int slot_t = t % Kw;
  if (tid == 0) {
    const float* zrow = p.z + (size_t)b * Gg;
    float e[Ll], mx, ssum, inv, run;
    mx = -1e30f;
    for (int l = 0; l < Ll; ++l) mx = fmaxf(mx, zrow[l]);
    ssum = 0.f;
    for (int l = 0; l < Ll; ++l) { e[l] = __expf(zrow[l] - mx); ssum += e[l]; }
    inv = 1.f / ssum; run = 0.f;
    float fmsum = 0.f;
    for (int l = 0; l < Ll; ++l) { run += e[l] * inv; sfm[l] = run; fmsum += run; }
    mx = -1e30f;
    for (int l = 0; l < Ll; ++l) mx = fmaxf(mx, zrow[Ll + l]);
    ssum = 0.f;
    for (int l = 0; l < Ll; ++l) { e[l] = __expf(zrow[Ll + l] - mx); ssum += e[l]; }
    inv = 1.f / ssum; run = 0.f;
    for (int l = Ll - 1; l >= 0; --l) { run += e[l] * inv; sim[l] = run; }
    float cdis = 1.f - fmsum * (1.f / Ll);
    p.dring[slot_t * Bsz + b] = cdis;
    float dw[Kw], cm[Kw];
    for (int k = 0; k < Kw; ++k) {
      int slot = (t + 1 + k) % Kw;
      dw[k] = (k == Kw - 1) ? cdis : p.dring[slot * Bsz + b];
    }
    float cs = 0.f, mx2 = -1e30f;
    for (int k = 0; k < Kw; ++k) { cs += dw[k]; cm[k] = cs; mx2 = fmaxf(mx2, cs); }
    float s2 = 0.f;
    for (int k = 0; k < Kw; ++k) { cm[k] = __expf(cm[k] - mx2); s2 += cm[k]; }
    float i2 = 1.f / s2;
    for (int k = 0; k < Kw; ++k) {
      float v = cm[k] * i2;
      sld[k] = v;
      p.ldis[(size_t)(t & 1) * (Bsz * Kw) + b * Kw + k] = v;
    }
  }
  __syncthreads();
  const float* zg = p.z + (size_t)b * Gg + 2 * Ll;
  for (int idx = tid; idx < Hh; idx += NTHR) {
    int l = idx / Cc;
    float f  = sigf(zg[idx]);
    float ii = sigf(zg[Hh + idx]);
    float oo = sigf(zg[2 * Hh + idx]);
    float ci = tanhfast(zg[3 * Hh + idx]);
    float cl = p.cbuf[(size_t)b * Hh + idx];
    float fm = sfm[l], im = sim[l], ov = fm * im;
    float cn = ov * (f * cl + ii * ci) + (fm - ov) * cl + (im - ov) * ci;
    float hn = oo * tanhfast(cn);
    p.cbuf[(size_t)b * Hh + idx] = cn;
    p.hring[(size_t)slot_t * (Bsz * Hh) + (size_t)b * Hh + idx] = hn;
    p.A1[(size_t)b * A1LD + Ff + idx] = f2bf(hn);   // h-part of next-step gemm1 A
    sh[idx] = hn;
  }
  if (t + 1 < Tt && tid < Ff)
    p.A1[(size_t)b * A1LD + tid] = f2bf(p.x[(size_t)b * (Tt * Ff) + (size_t)(t + 1) * Ff + tid]);
  __syncthreads();
  // Ab[b][k*768+c] = h_win[k][c]*ld[k]  (bf16) ; hmb = bf16 mean over k
  for (int idx = tid; idx < Hh; idx += NTHR) {
    float a = 0.f;
    #pragma unroll
    for (int k = 0; k < Kw; ++k) {
      int slot = (t + 1 + k) % Kw;
      float hv = (k == Kw - 1) ? sh[idx]
                               : p.hring[(size_t)slot * (Bsz * Hh) + (size_t)b * Hh + idx];
      float v = hv * sld[k];
      p.Ab[(size_t)b * KC + (size_t)k * Hh + idx] = f2bf(v);
      a += v;
    }
    p.hmb[(size_t)b * Hh + idx] = f2bf(a * (1.f / Kw));
  }
}

__device__ void combine_phase(const SP& p, int b0, int t, float* misc) {
  const int tid = threadIdx.x;
  float* st1  = misc;
  float* sred = misc + 512;
  for (int i = tid; i < 4 * Ss; i += NTHR) st1[i] = p.th1[(size_t)b0 * Ss + i];
  __syncthreads();
  const int slot_t = t % Kw;
  float dot0 = 0, dot1 = 0, dot2 = 0, dot3 = 0;
  for (int o = tid; o < Hh; o += NTHR) {
    float rb = p.rsb[o];
    float t0 = rb, t1 = rb, t2 = rb, t3 = rb;
    for (int s = 0; s < Ss; ++s) {
      float w = p.rsw[(size_t)s * Hh + o];
      t0 = fmaf(st1[s], w, t0);
      t1 = fmaf(st1[Ss + s], w, t1);
      t2 = fmaf(st1[2 * Ss + s], w, t2);
      t3 = fmaf(st1[3 * Ss + s], w, t3);
    }
    float cbv = p.cb[o];
    float c0 = cbv, c1 = cbv, c2 = cbv, c3 = cbv;
    for (int ks = 0; ks < SPLITS; ++ks) {
      const float* cp = p.cpart + (size_t)ks * (Bsz * Hh) + (size_t)b0 * Hh + o;
      c0 += cp[0]; c1 += cp[Hh]; c2 += cp[2 * (size_t)Hh]; c3 += cp[3 * (size_t)Hh];
    }
    float oww = p.ow[o];
    const float* hr = p.hring + (size_t)slot_t * (Bsz * Hh) + (size_t)b0 * Hh + o;
    dot0 += (sigf(t0) * c0 + hr[0]) * oww;
    dot1 += (sigf(t1) * c1 + hr[Hh]) * oww;
    dot2 += (sigf(t2) * c2 + hr[2 * (size_t)Hh]) * oww;
    dot3 += (sigf(t3) * c3 + hr[3 * (size_t)Hh]) * oww;
  }
  float d[4] = {dot0, dot1, dot2, dot3};
  #pragma unroll
  for (int q = 0; q < 4; ++q) {
    float v = d[q];
    for (int off = 32; off > 0; off >>= 1) v += __shfl_down(v, off);
    if ((tid & 63) == 0) sred[(tid >> 6) * 4 + q] = v;
  }
  __syncthreads();
  if (tid < 4) {
    float v = sred[tid] + sred[4 + tid] + sred[8 + tid] + sred[12 + tid];
    p.out[(size_t)(b0 + tid) * Tt + t] = sigf(v + p.ob[0]);
  }
}

// ---------------- step kernels ----------------
__global__ void __launch_bounds__(NTHR, 2) k_p1(SP p, int t) {
  __shared__ float misc[Hh + 64];
  const int blk = blockIdx.x;
  if (blk < Bsz) gates_phase(p, blk, t, misc);
  else if (t > 0) combine_phase(p, (blk - 256) * 4, t - 1, misc);
}

__device__ __forceinline__ void do_gemm1(const SP& p, int j, ushort* lsA, ushort* lsB) {
  const int bt = j / 25, nt = j % 25;
  const int m0 = bt * 128, n0 = nt * 128;
  f32x4 acc[4][4] = {};
  mfma_tile(p.A1 + (size_t)m0 * A1LD, A1LD, p.kwb + (size_t)n0 * A1LD, A1LD,
            0, A1LD / 32, lsA, lsB, acc);
  const int lane = threadIdx.x & 63, wid = threadIdx.x >> 6;
  const int wm = (wid >> 1) * 64, wn = (wid & 1) * 64;
  const int lr = lane & 15, lg = lane >> 4;
  #pragma unroll
  for (int mf = 0; mf < 4; ++mf)
    #pragma unroll
    for (int nf = 0; nf < 4; ++nf) {
      int gc = n0 + wn + nf * 16 + lr;
      if (gc < Gg) {
        float zb = p.zbias[gc];
        #pragma unroll
        for (int r = 0; r < 4; ++r) {
          int gr = m0 + wm + mf * 16 + lg * 4 + r;
          p.z[(size_t)gr * Gg + gc] = acc[mf][nf][r] + zb;
        }
      }
    }
}

__global__ void __launch_bounds__(NTHR, 2) k_p2(SP p, int t) {
  __shared__ ushort lsA[128 * 32];
  __shared__ ushort lsB[128 * 32];
  const int j = blockIdx.x;
  const int lane = threadIdx.x & 63, wid = threadIdx.x >> 6;
  const int wm = (wid >> 1) * 64, wn = (wid & 1) * 64;
  const int lr = lane & 15, lg = lane >> 4;
  if (j < CONV_JOBS) {
    const int bt = j / 96, r = j % 96, ot = r / SPLITS, sp = r % SPLITS;
    const int m0 = bt * 128, n0 = ot * 128, k0 = sp * (KC / SPLITS);
    f32x4 acc[4][4] = {};
    mfma_tile(p.Ab + (size_t)m0 * KC, KC, p.cwtb + (size_t)n0 * KC, KC,
              k0, (KC / SPLITS) / 32, lsA, lsB, acc);
    float* dst = p.cpart + (size_t)sp * (Bsz * Hh);
    #pragma unroll
    for (int mf = 0; mf < 4; ++mf)
      #pragma unroll
      for (int nf = 0; nf < 4; ++nf) {
        int gc = n0 + wn + nf * 16 + lr;
        #pragma unroll
        for (int rr = 0; rr < 4; ++rr) {
          int gr = m0 + wm + mf * 16 + lg * 4 + rr;
          dst[(size_t)gr * Hh + gc] = acc[mf][nf][rr];
        }
      }
  } else if (j < CONV_JOBS + G1_JOBS) {
    if (t + 1 < Tt) do_gemm1(p, j - CONV_JOBS, lsA, lsB);
  } else {
    const int jj = j - CONV_JOBS - G1_JOBS;
    const int m0 = jj * 128;
    f32x4 acc[4][4] = {};
    mfma_tile(p.hmb + (size_t)m0 * Hh, Hh, p.swb, Hh, 0, Hh / 32, lsA, lsB, acc);
    #pragma unroll
    for (int mf = 0; mf < 4; ++mf)
      #pragma unroll
      for (int nf = 0; nf < 4; ++nf) {
        int s = wn + nf * 16 + lr;
        float sb = p.sb[s];
        #pragma unroll
        for (int rr = 0; rr < 4; ++rr) {
          int gr = m0 + wm + mf * 16 + lg * 4 + rr;
          p.th1[(size_t)gr * Ss + s] = fmaxf(acc[mf][nf][rr] + sb, 0.f);
        }
      }
  }
}

__global__ void __launch_bounds__(NTHR, 2) k_g1first(SP p) {
  __shared__ ushort lsA[128 * 32];
  __shared__ ushort lsB[128 * 32];
  do_gemm1(p, blockIdx.x, lsA, lsB);
}

__global__ void __launch_bounds__(NTHR, 2) k_comb_last(SP p) {
  __shared__ float misc[Hh + 64];
  combine_phase(p, blockIdx.x * 4, Tt - 1, misc);
}

// ---------------- host entry ----------------
extern "C" void kernel_launch(void* const* d_in, const int* in_sizes, int n_in,
                              void* d_out, int out_size, void* d_ws, size_t ws_size,
                              hipStream_t stream) {
  (void)in_sizes; (void)n_in;
  SP p;
  p.x   = (const float*)d_in[0];
  p.kw  = (const float*)d_in[1];
  p.kb  = (const float*)d_in[2];
  p.rw  = (const float*)d_in[3];
  p.rb  = (const float*)d_in[4];
  p.sw  = (const float*)d_in[5];
  p.sb  = (const float*)d_in[6];
  p.rsw = (const float*)d_in[7];
  p.rsb = (const float*)d_in[8];
  p.cw  = (const float*)d_in[9];
  p.cb  = (const float*)d_in[10];
  p.ow  = (const float*)d_in[11];
  p.ob  = (const float*)d_in[12];
  float* ws = (float*)d_ws;
  p.z = ws + O_Z; p.zbias = ws + O_ZB; p.hring = ws + O_HR; p.cbuf = ws + O_CB;
  p.dring = ws + O_DR; p.ldis = ws + O_LD; p.th1 = ws + O_TH1; p.cpart = ws + O_CP;
  ushort* wsb = (ushort*)(ws + O_BF);
  p.kwb = wsb + H_KWB; p.cwtb = wsb + H_CWT; p.swb = wsb + H_SWB;
  p.A1 = wsb + H_A1; p.Ab = wsb + H_AB; p.hmb = wsb + H_HM;
  p.out = (float*)d_out;

  if (ws_size < WS_FL * sizeof(float)) {
    k_fill<<<(out_size + NTHR - 1) / NTHR, NTHR, 0, stream>>>((float*)d_out, out_size, 0.5f);
    return;
  }

  k_setup<<<1024, NTHR, 0, stream>>>(p);
  k_wkr<<<1024, NTHR, 0, stream>>>(p);
  k_wconv<<<2048, NTHR, 0, stream>>>(p);
  k_wsw<<<256, NTHR, 0, stream>>>(p);
  k_g1first<<<G1_JOBS, NTHR, 0, stream>>>(p);                 // z(0)
  for (int t = 0; t < Tt; ++t) {
    k_p1<<<320, NTHR, 0, stream>>>(p, t);                     // gates(t) || combine(t-1)
    k_p2<<<P2_GRID, NTHR, 0, stream>>>(p, t);                 // conv(t)+theme1(t)+z(t+1)
  }
  k_comb_last<<<64, NTHR, 0, stream>>>(p);                    // combine(399)
}